// Round 2
// baseline (568.699 us; speedup 1.0000x reference)
//
#include <hip/hip_runtime.h>

#define NN 25000
#define EE 400000
#define FIN 133
#define HCC 512

// ---------------- zero the degree counters (ws is poisoned each call) ------
__global__ __launch_bounds__(256) void k_zero(int* __restrict__ cnt) {
    int i = blockIdx.x * 256 + threadIdx.x;
    if (i < NN) cnt[i] = 0;
}

// ---------------- fused xl|xr GEMM: 128x128 tile, 8x8/thread, BK=16 -------
// grid = (8 col tiles over combined 1024, 196 row tiles). bx fastest so the
// 8 blocks sharing a row panel are co-resident -> x fetched ~once from HBM.
#define BM 128
#define BN 128
#define BK 16

__global__ __launch_bounds__(256) void k_gemm2(
    const float* __restrict__ x, const float* __restrict__ Wl,
    const float* __restrict__ Wr, float* __restrict__ xl, float* __restrict__ xr)
{
    __shared__ float As[BK][BM + 4];   // [kk][r], pad 4 keeps float4 align (528B rows)
    __shared__ float Bs[BK][BN + 4];   // [kk][c]
    const int tid = threadIdx.x;
    const int cbase = blockIdx.x * BN;           // combined col 0..1023
    const int row0 = blockIdx.y * BM;
    const bool isR = cbase >= HCC;
    const float* __restrict__ W = isR ? Wr : Wl;
    float* __restrict__ outp = isR ? xr : xl;
    const int wc0 = isR ? cbase - HCC : cbase;

    const int tr = tid >> 4;                     // 0..15
    const int tc = tid & 15;
    const int r0 = tr * 8, c0 = tc * 8;

    float acc[8][8] = {};

    for (int k0 = 0; k0 < FIN; k0 += BK) {       // 9 steps (last zero-padded)
        // stage As[kk][r]: kk consecutive per lane -> 64B global segments,
        // LDS store stride 132 floats -> 2-way max (free)
        #pragma unroll
        for (int i = 0; i < 8; ++i) {
            int idx = tid + i * 256;             // 0..2047
            int r = idx >> 4, kk = idx & 15;
            int row = row0 + r, k = k0 + kk;
            As[kk][r] = (row < NN && k < FIN) ? x[(size_t)row * FIN + k] : 0.f;
        }
        // stage Bs: float4 coalesced (W row stride 512 floats, 16B aligned)
        #pragma unroll
        for (int i = 0; i < 2; ++i) {
            int idx = tid + i * 256;             // unit = float4, 0..511
            int kk = idx >> 5;
            int c4 = (idx & 31) * 4;
            int k = k0 + kk;
            float4 v = make_float4(0.f, 0.f, 0.f, 0.f);
            if (k < FIN) v = *(const float4*)&W[(size_t)k * HCC + wc0 + c4];
            *(float4*)&Bs[kk][c4] = v;
        }
        __syncthreads();
        #pragma unroll
        for (int kk = 0; kk < BK; ++kk) {
            float a[8], b[8];
            *(float4*)&a[0] = *(const float4*)&As[kk][r0];
            *(float4*)&a[4] = *(const float4*)&As[kk][r0 + 4];
            *(float4*)&b[0] = *(const float4*)&Bs[kk][c0];
            *(float4*)&b[4] = *(const float4*)&Bs[kk][c0 + 4];
            #pragma unroll
            for (int i = 0; i < 8; ++i)
                #pragma unroll
                for (int j = 0; j < 8; ++j) acc[i][j] += a[i] * b[j];
        }
        __syncthreads();
    }
    #pragma unroll
    for (int i = 0; i < 8; ++i) {
        int row = row0 + r0 + i;
        if (row < NN) {
            *(float4*)&outp[(size_t)row * HCC + wc0 + c0] =
                make_float4(acc[i][0], acc[i][1], acc[i][2], acc[i][3]);
            *(float4*)&outp[(size_t)row * HCC + wc0 + c0 + 4] =
                make_float4(acc[i][4], acc[i][5], acc[i][6], acc[i][7]);
        }
    }
}

// ---------------- in-degree histogram over dst ----------------------------
__global__ __launch_bounds__(256) void k_count(const int* __restrict__ dst,
                                               int* __restrict__ cnt) {
    int e = blockIdx.x * 256 + threadIdx.x;
    if (e < EE) atomicAdd(&cnt[dst[e]], 1);
}

// ---------------- exclusive scan (single block, wave-shuffle) + dinv ------
__global__ __launch_bounds__(256) void k_scan(const int* __restrict__ cnt,
    int* __restrict__ offs, int* __restrict__ cursor, float* __restrict__ dinv)
{
    __shared__ int wsum[4];
    __shared__ int carry_s;
    const int tid = threadIdx.x;
    const int lane = tid & 63, wid = tid >> 6;
    if (tid == 0) carry_s = 0;
    __syncthreads();
    for (int base = 0; base < NN; base += 1024) {
        int i0 = base + tid * 4;
        int v[4];
        #pragma unroll
        for (int j = 0; j < 4; ++j) {
            int i = i0 + j;
            v[j] = (i < NN) ? cnt[i] : 0;
            if (i < NN) dinv[i] = rsqrtf((float)(v[j] + 1));  // deg incl self loop
        }
        int tsum = v[0] + v[1] + v[2] + v[3];
        int s = tsum;
        #pragma unroll
        for (int off = 1; off < 64; off <<= 1) {
            int t = __shfl_up(s, off);
            if (lane >= off) s += t;
        }
        if (lane == 63) wsum[wid] = s;
        __syncthreads();
        int wcarry = carry_s;
        for (int w = 0; w < wid; ++w) wcarry += wsum[w];
        int ex = wcarry + s - tsum;
        #pragma unroll
        for (int j = 0; j < 4; ++j) {
            int i = i0 + j;
            if (i < NN) { offs[i] = ex; cursor[i] = ex; }
            ex += v[j];
        }
        __syncthreads();
        if (tid == 255) carry_s = wcarry + s;
        __syncthreads();
    }
    if (tid == 0) offs[NN] = carry_s;
}

// ---------------- scatter edges into CSR (by dst) -------------------------
__global__ __launch_bounds__(256) void k_scatter(const int* __restrict__ src,
    const int* __restrict__ dst, int* __restrict__ cursor, int* __restrict__ csr)
{
    int e = blockIdx.x * 256 + threadIdx.x;
    if (e < EE) {
        int d = dst[e];
        int pos = atomicAdd(&cursor[d], 1);
        csr[pos] = src[e];
    }
}

// ---------------- GATv2 per-node (one wave per dst) + BN/PReLU/Wg ---------
__global__ __launch_bounds__(256) void k_gat(
    const float* __restrict__ xl, const float* __restrict__ xr,
    const float* __restrict__ att, const float* __restrict__ b1,
    const float* __restrict__ gam, const float* __restrict__ bet,
    const float* __restrict__ mean, const float* __restrict__ var,
    const float* __restrict__ pw, const float* __restrict__ Wg,
    const int* __restrict__ offs, const int* __restrict__ csr,
    float* __restrict__ h2)
{
    const int lane = threadIdx.x & 63;
    const int node = blockIdx.x * 4 + (threadIdx.x >> 6);  // grid = NN/4 exactly
    const int sb = lane * 8;                               // 8 contiguous ch, one head
    float4 xr0 = *(const float4*)&xr[(size_t)node * HCC + sb];
    float4 xr1 = *(const float4*)&xr[(size_t)node * HCC + sb + 4];
    float4 a0 = *(const float4*)&att[sb];
    float4 a1 = *(const float4*)&att[sb + 4];
    float m = -3.0e38f, s = 0.f;
    float acc[8] = {0.f, 0.f, 0.f, 0.f, 0.f, 0.f, 0.f, 0.f};
    const int beg = offs[node], end = offs[node + 1];
    auto lrelu = [](float t) { return t >= 0.f ? t : 0.2f * t; };
    auto process = [&](int srcn) {
        const float* p = &xl[(size_t)srcn * HCC + sb];
        float4 v0 = *(const float4*)p;
        float4 v1 = *(const float4*)(p + 4);
        float ep = lrelu(v0.x + xr0.x) * a0.x + lrelu(v0.y + xr0.y) * a0.y
                 + lrelu(v0.z + xr0.z) * a0.z + lrelu(v0.w + xr0.w) * a0.w
                 + lrelu(v1.x + xr1.x) * a1.x + lrelu(v1.y + xr1.y) * a1.y
                 + lrelu(v1.z + xr1.z) * a1.z + lrelu(v1.w + xr1.w) * a1.w;
        ep += __shfl_xor(ep, 1);
        ep += __shfl_xor(ep, 2);
        ep += __shfl_xor(ep, 4);        // head logit, replicated in 8-lane group
        float mn = fmaxf(m, ep);
        float sc = __expf(m - mn);
        float w  = __expf(ep - mn);
        s = s * sc + w;
        float vv[8] = {v0.x, v0.y, v0.z, v0.w, v1.x, v1.y, v1.z, v1.w};
        #pragma unroll
        for (int k = 0; k < 8; ++k) acc[k] = acc[k] * sc + w * vv[k];
        m = mn;
    };
    process(node);                          // self loop
    for (int j = beg; j < end; ++j) process(csr[j]);
    float inv = 1.f / s;
    float p_w = pw[0];
    float dot = 0.f;
    #pragma unroll
    for (int k = 0; k < 8; ++k) {
        int idx = sb + k;
        float v = acc[k] * inv + b1[idx];
        v = (v - mean[idx]) * rsqrtf(var[idx] + 1e-5f) * gam[idx] + bet[idx];
        v = v >= 0.f ? v : p_w * v;
        dot += v * Wg[idx];
    }
    dot += __shfl_xor(dot, 1);
    dot += __shfl_xor(dot, 2);
    dot += __shfl_xor(dot, 4);
    dot += __shfl_xor(dot, 8);
    dot += __shfl_xor(dot, 16);
    dot += __shfl_xor(dot, 32);
    if (lane == 0) h2[node] = dot;
}

// ---------------- GCN: out[n] = dinv[n]*sum(dinv[src]*h2[src]) + bg -------
__global__ __launch_bounds__(256) void k_gcn(
    const float* __restrict__ h2, const float* __restrict__ dinv,
    const int* __restrict__ offs, const int* __restrict__ csr,
    const float* __restrict__ bg, float* __restrict__ out)
{
    int n = blockIdx.x * 256 + threadIdx.x;
    if (n >= NN) return;
    float dn = dinv[n];
    float s = dn * h2[n];                   // self loop
    int e0 = offs[n], e1 = offs[n + 1];
    for (int j = e0; j < e1; ++j) {
        int src = csr[j];
        s += dinv[src] * h2[src];
    }
    out[n] = dn * s + bg[0];
}

extern "C" void kernel_launch(void* const* d_in, const int* in_sizes, int n_in,
                              void* d_out, int out_size, void* d_ws, size_t ws_size,
                              hipStream_t stream)
{
    const float* x    = (const float*)d_in[0];
    const int*   ei   = (const int*)d_in[1];
    const float* Wl   = (const float*)d_in[2];
    const float* Wr   = (const float*)d_in[3];
    const float* att  = (const float*)d_in[4];
    const float* b1   = (const float*)d_in[5];
    const float* gam  = (const float*)d_in[6];
    const float* bet  = (const float*)d_in[7];
    const float* mean = (const float*)d_in[8];
    const float* var  = (const float*)d_in[9];
    const float* pw   = (const float*)d_in[10];
    const float* Wg   = (const float*)d_in[11];
    const float* bg   = (const float*)d_in[12];
    float* out = (float*)d_out;

    float* xl   = (float*)d_ws;             // 51.2 MB
    float* xr   = xl + (size_t)NN * HCC;    // 51.2 MB
    float* h2   = xr + (size_t)NN * HCC;    // 100 KB
    float* dinv = h2 + NN;                  // 100 KB
    int*   cnt  = (int*)(dinv + NN);        // 100 KB
    int*   offs = cnt + NN;                 // 100 KB
    int*   cursor = offs + NN + 1;          // 100 KB
    int*   csr  = cursor + NN;              // 1.6 MB

    const int* srcp = ei;
    const int* dstp = ei + EE;

    k_zero<<<(NN + 255) / 256, 256, 0, stream>>>(cnt);
    dim3 gg(1024 / BN, (NN + BM - 1) / BM, 1);
    k_gemm2<<<gg, 256, 0, stream>>>(x, Wl, Wr, xl, xr);
    k_count<<<(EE + 255) / 256, 256, 0, stream>>>(dstp, cnt);
    k_scan<<<1, 256, 0, stream>>>(cnt, offs, cursor, dinv);
    k_scatter<<<(EE + 255) / 256, 256, 0, stream>>>(srcp, dstp, cursor, csr);
    k_gat<<<NN / 4, 256, 0, stream>>>(xl, xr, att, b1, gam, bet, mean, var, pw, Wg,
                                      offs, csr, h2);
    k_gcn<<<(NN + 255) / 256, 256, 0, stream>>>(h2, dinv, offs, csr, bg, out);
}

// Round 3
// 432.123 us; speedup vs baseline: 1.3161x; 1.3161x over previous
//
#include <hip/hip_runtime.h>

#define NN 25000
#define EE 400000
#define FIN 133
#define HCC 512

// ---------------- zero the degree counters (ws is poisoned each call) ------
__global__ __launch_bounds__(256) void k_zero(int* __restrict__ cnt) {
    int i = blockIdx.x * 256 + threadIdx.x;
    if (i < NN) cnt[i] = 0;
}

// ---------------- fused xl|xr GEMM: 128x64 tile, 8x4/thread, BK=16 --------
// grid.x = 16 col tiles over combined 1024 cols (fastest) -> 16 blocks share
// a row panel of x in L2. 8x4 acc keeps VGPR < 128 (4 waves/SIMD tier).
#define BM 128
#define BN 64
#define BK 16

__global__ __launch_bounds__(256, 4) void k_gemm2(
    const float* __restrict__ x, const float* __restrict__ Wl,
    const float* __restrict__ Wr, float* __restrict__ xl, float* __restrict__ xr)
{
    __shared__ float As[BK][BM + 4];   // [kk][r]  132-float rows
    __shared__ float Bs[BK][BN + 4];   // [kk][c]  68-float rows
    const int tid = threadIdx.x;
    const int cbase = blockIdx.x * BN;           // combined col 0..1023
    const int row0 = blockIdx.y * BM;
    const bool isR = cbase >= HCC;
    const float* __restrict__ W = isR ? Wr : Wl;
    float* __restrict__ outp = isR ? xr : xl;
    const int wc0 = isR ? cbase - HCC : cbase;

    const int tr = tid >> 4;                     // 0..15
    const int tc = tid & 15;                     // 0..15
    const int r0 = tr * 8, c0 = tc * 4;

    float acc[8][4] = {};

    for (int k0 = 0; k0 < FIN; k0 += BK) {       // 9 steps (tail zero-padded)
        // stage As[kk][r]: lane i loads x[row0 + (i>>4)][k0 + (i&15)] ->
        // 64B global segments; LDS bank = (4*kk + r) & 31 -> 2-way (free)
        #pragma unroll
        for (int i = 0; i < 8; ++i) {
            int idx = tid + i * 256;             // 0..2047
            int r = idx >> 4, kk = idx & 15;
            int row = row0 + r, k = k0 + kk;
            As[kk][r] = (row < NN && k < FIN) ? x[(size_t)row * FIN + k] : 0.f;
        }
        // stage Bs: one float4 per thread, 16 lanes = 256B contiguous
        {
            int kk = tid >> 4;
            int c4 = (tid & 15) * 4;
            int k = k0 + kk;
            float4 v = make_float4(0.f, 0.f, 0.f, 0.f);
            if (k < FIN) v = *(const float4*)&W[(size_t)k * HCC + wc0 + c4];
            *(float4*)&Bs[kk][c4] = v;
        }
        __syncthreads();
        #pragma unroll
        for (int kk = 0; kk < BK; ++kk) {
            float a[8], b[4];
            *(float4*)&a[0] = *(const float4*)&As[kk][r0];
            *(float4*)&a[4] = *(const float4*)&As[kk][r0 + 4];
            *(float4*)&b[0] = *(const float4*)&Bs[kk][c0];
            #pragma unroll
            for (int i = 0; i < 8; ++i)
                #pragma unroll
                for (int j = 0; j < 4; ++j) acc[i][j] += a[i] * b[j];
        }
        __syncthreads();
    }
    #pragma unroll
    for (int i = 0; i < 8; ++i) {
        int row = row0 + r0 + i;
        if (row < NN) {
            *(float4*)&outp[(size_t)row * HCC + wc0 + c0] =
                make_float4(acc[i][0], acc[i][1], acc[i][2], acc[i][3]);
        }
    }
}

// ---------------- in-degree histogram over dst ----------------------------
__global__ __launch_bounds__(256) void k_count(const int* __restrict__ dst,
                                               int* __restrict__ cnt) {
    int e = blockIdx.x * 256 + threadIdx.x;
    if (e < EE) atomicAdd(&cnt[dst[e]], 1);
}

// ---------------- exclusive scan (single block, wave-shuffle) + dinv ------
__global__ __launch_bounds__(256) void k_scan(const int* __restrict__ cnt,
    int* __restrict__ offs, int* __restrict__ cursor, float* __restrict__ dinv)
{
    __shared__ int wsum[4];
    __shared__ int carry_s;
    const int tid = threadIdx.x;
    const int lane = tid & 63, wid = tid >> 6;
    if (tid == 0) carry_s = 0;
    __syncthreads();
    for (int base = 0; base < NN; base += 1024) {
        int i0 = base + tid * 4;
        int v[4];
        #pragma unroll
        for (int j = 0; j < 4; ++j) {
            int i = i0 + j;
            v[j] = (i < NN) ? cnt[i] : 0;
            if (i < NN) dinv[i] = rsqrtf((float)(v[j] + 1));  // deg incl self loop
        }
        int tsum = v[0] + v[1] + v[2] + v[3];
        int s = tsum;
        #pragma unroll
        for (int off = 1; off < 64; off <<= 1) {
            int t = __shfl_up(s, off);
            if (lane >= off) s += t;
        }
        if (lane == 63) wsum[wid] = s;
        __syncthreads();
        int wcarry = carry_s;
        for (int w = 0; w < wid; ++w) wcarry += wsum[w];
        int ex = wcarry + s - tsum;
        #pragma unroll
        for (int j = 0; j < 4; ++j) {
            int i = i0 + j;
            if (i < NN) { offs[i] = ex; cursor[i] = ex; }
            ex += v[j];
        }
        __syncthreads();
        if (tid == 255) carry_s = wcarry + s;
        __syncthreads();
    }
    if (tid == 0) offs[NN] = carry_s;
}

// ---------------- scatter edges into CSR (by dst) -------------------------
__global__ __launch_bounds__(256) void k_scatter(const int* __restrict__ src,
    const int* __restrict__ dst, int* __restrict__ cursor, int* __restrict__ csr)
{
    int e = blockIdx.x * 256 + threadIdx.x;
    if (e < EE) {
        int d = dst[e];
        int pos = atomicAdd(&cursor[d], 1);
        csr[pos] = src[e];
    }
}

// ---------------- GATv2 per-node (one wave per dst) + BN/PReLU/Wg ---------
__global__ __launch_bounds__(256) void k_gat(
    const float* __restrict__ xl, const float* __restrict__ xr,
    const float* __restrict__ att, const float* __restrict__ b1,
    const float* __restrict__ gam, const float* __restrict__ bet,
    const float* __restrict__ mean, const float* __restrict__ var,
    const float* __restrict__ pw, const float* __restrict__ Wg,
    const int* __restrict__ offs, const int* __restrict__ csr,
    float* __restrict__ h2)
{
    const int lane = threadIdx.x & 63;
    const int node = blockIdx.x * 4 + (threadIdx.x >> 6);  // grid = NN/4 exactly
    const int sb = lane * 8;                               // 8 contiguous ch, one head
    float4 xr0 = *(const float4*)&xr[(size_t)node * HCC + sb];
    float4 xr1 = *(const float4*)&xr[(size_t)node * HCC + sb + 4];
    float4 a0 = *(const float4*)&att[sb];
    float4 a1 = *(const float4*)&att[sb + 4];
    float m = -3.0e38f, s = 0.f;
    float acc[8] = {0.f, 0.f, 0.f, 0.f, 0.f, 0.f, 0.f, 0.f};
    const int beg = offs[node], end = offs[node + 1];
    auto lrelu = [](float t) { return t >= 0.f ? t : 0.2f * t; };
    auto process = [&](int srcn) {
        const float* p = &xl[(size_t)srcn * HCC + sb];
        float4 v0 = *(const float4*)p;
        float4 v1 = *(const float4*)(p + 4);
        float ep = lrelu(v0.x + xr0.x) * a0.x + lrelu(v0.y + xr0.y) * a0.y
                 + lrelu(v0.z + xr0.z) * a0.z + lrelu(v0.w + xr0.w) * a0.w
                 + lrelu(v1.x + xr1.x) * a1.x + lrelu(v1.y + xr1.y) * a1.y
                 + lrelu(v1.z + xr1.z) * a1.z + lrelu(v1.w + xr1.w) * a1.w;
        ep += __shfl_xor(ep, 1);
        ep += __shfl_xor(ep, 2);
        ep += __shfl_xor(ep, 4);        // head logit, replicated in 8-lane group
        float mn = fmaxf(m, ep);
        float sc = __expf(m - mn);
        float w  = __expf(ep - mn);
        s = s * sc + w;
        float vv[8] = {v0.x, v0.y, v0.z, v0.w, v1.x, v1.y, v1.z, v1.w};
        #pragma unroll
        for (int k = 0; k < 8; ++k) acc[k] = acc[k] * sc + w * vv[k];
        m = mn;
    };
    process(node);                          // self loop
    for (int j = beg; j < end; ++j) process(csr[j]);
    float inv = 1.f / s;
    float p_w = pw[0];
    float dot = 0.f;
    #pragma unroll
    for (int k = 0; k < 8; ++k) {
        int idx = sb + k;
        float v = acc[k] * inv + b1[idx];
        v = (v - mean[idx]) * rsqrtf(var[idx] + 1e-5f) * gam[idx] + bet[idx];
        v = v >= 0.f ? v : p_w * v;
        dot += v * Wg[idx];
    }
    dot += __shfl_xor(dot, 1);
    dot += __shfl_xor(dot, 2);
    dot += __shfl_xor(dot, 4);
    dot += __shfl_xor(dot, 8);
    dot += __shfl_xor(dot, 16);
    dot += __shfl_xor(dot, 32);
    if (lane == 0) h2[node] = dot;
}

// ---------------- GCN: out[n] = dinv[n]*sum(dinv[src]*h2[src]) + bg -------
__global__ __launch_bounds__(256) void k_gcn(
    const float* __restrict__ h2, const float* __restrict__ dinv,
    const int* __restrict__ offs, const int* __restrict__ csr,
    const float* __restrict__ bg, float* __restrict__ out)
{
    int n = blockIdx.x * 256 + threadIdx.x;
    if (n >= NN) return;
    float dn = dinv[n];
    float s = dn * h2[n];                   // self loop
    int e0 = offs[n], e1 = offs[n + 1];
    for (int j = e0; j < e1; ++j) {
        int src = csr[j];
        s += dinv[src] * h2[src];
    }
    out[n] = dn * s + bg[0];
}

extern "C" void kernel_launch(void* const* d_in, const int* in_sizes, int n_in,
                              void* d_out, int out_size, void* d_ws, size_t ws_size,
                              hipStream_t stream)
{
    const float* x    = (const float*)d_in[0];
    const int*   ei   = (const int*)d_in[1];
    const float* Wl   = (const float*)d_in[2];
    const float* Wr   = (const float*)d_in[3];
    const float* att  = (const float*)d_in[4];
    const float* b1   = (const float*)d_in[5];
    const float* gam  = (const float*)d_in[6];
    const float* bet  = (const float*)d_in[7];
    const float* mean = (const float*)d_in[8];
    const float* var  = (const float*)d_in[9];
    const float* pw   = (const float*)d_in[10];
    const float* Wg   = (const float*)d_in[11];
    const float* bg   = (const float*)d_in[12];
    float* out = (float*)d_out;

    float* xl   = (float*)d_ws;             // 51.2 MB
    float* xr   = xl + (size_t)NN * HCC;    // 51.2 MB
    float* h2   = xr + (size_t)NN * HCC;    // 100 KB
    float* dinv = h2 + NN;                  // 100 KB
    int*   cnt  = (int*)(dinv + NN);        // 100 KB
    int*   offs = cnt + NN;                 // 100 KB
    int*   cursor = offs + NN + 1;          // 100 KB
    int*   csr  = cursor + NN;              // 1.6 MB

    const int* srcp = ei;
    const int* dstp = ei + EE;

    k_zero<<<(NN + 255) / 256, 256, 0, stream>>>(cnt);
    dim3 gg(1024 / BN, (NN + BM - 1) / BM, 1);
    k_gemm2<<<gg, 256, 0, stream>>>(x, Wl, Wr, xl, xr);
    k_count<<<(EE + 255) / 256, 256, 0, stream>>>(dstp, cnt);
    k_scan<<<1, 256, 0, stream>>>(cnt, offs, cursor, dinv);
    k_scatter<<<(EE + 255) / 256, 256, 0, stream>>>(srcp, dstp, cursor, csr);
    k_gat<<<NN / 4, 256, 0, stream>>>(xl, xr, att, b1, gam, bet, mean, var, pw, Wg,
                                      offs, csr, h2);
    k_gcn<<<(NN + 255) / 256, 256, 0, stream>>>(h2, dinv, offs, csr, bg, out);
}

// Round 4
// 361.178 us; speedup vs baseline: 1.5746x; 1.1964x over previous
//
#include <hip/hip_runtime.h>

#define NN 25000
#define EE 400000
#define FIN 133
#define HCC 512
#define RPAD 25088          // rows padded to 196*128
#define KPAD 160            // K padded to 5*32
#define NT 5                // K-steps of 32

typedef __attribute__((ext_vector_type(8))) __bf16 bf16x8;
typedef __attribute__((ext_vector_type(4))) float f32x4;

static __device__ __forceinline__ ushort f2bf(float f) {
    uint32_t u = __float_as_uint(f);
    uint32_t r = (u + 0x7fffu + ((u >> 16) & 1u)) >> 16;   // RNE
    return (ushort)r;
}
static __device__ __forceinline__ float bf2f(ushort b) {
    return __uint_as_float(((uint32_t)b) << 16);
}

// ---------------- zero the degree counters (ws is poisoned each call) ------
__global__ __launch_bounds__(256) void k_zero(int* __restrict__ cnt) {
    int i = blockIdx.x * 256 + threadIdx.x;
    if (i < NN) cnt[i] = 0;
}

// ---- convert x -> blocked bf16 hi/lo: slot[(t*4+kg)*RPAD + row] = 8 k's ---
__global__ __launch_bounds__(256) void k_cvt_x(const float* __restrict__ x,
    ushort* __restrict__ ah, ushort* __restrict__ al)
{
    const int row = blockIdx.x * 256 + threadIdx.x;   // < RPAD (grid 98)
    const int oct = blockIdx.y;                       // 0..19, k base = oct*8
    const int kb = oct * 8;
    ushort h[8], l[8];
    #pragma unroll
    for (int j = 0; j < 8; ++j) {
        int k = kb + j;
        float v = (row < NN && k < FIN) ? x[(size_t)row * FIN + k] : 0.f;
        ushort hh = f2bf(v);
        h[j] = hh;
        l[j] = f2bf(v - bf2f(hh));
    }
    uint4 H, L;
    H.x = h[0] | (h[1] << 16); H.y = h[2] | (h[3] << 16);
    H.z = h[4] | (h[5] << 16); H.w = h[6] | (h[7] << 16);
    L.x = l[0] | (l[1] << 16); L.y = l[2] | (l[3] << 16);
    L.z = l[4] | (l[5] << 16); L.w = l[6] | (l[7] << 16);
    size_t slot = (size_t)oct * RPAD + row;
    ((uint4*)ah)[slot] = H;
    ((uint4*)al)[slot] = L;
}

// ---- convert [Wl|Wr] -> blocked bf16 hi/lo: slot[oct*1024 + col] ----------
__global__ __launch_bounds__(256) void k_cvt_w(
    const float* __restrict__ Wl, const float* __restrict__ Wr,
    ushort* __restrict__ wh, ushort* __restrict__ wl)
{
    const int col = blockIdx.x * 256 + threadIdx.x;   // 0..1023
    const int oct = blockIdx.y;                       // 0..19
    const int kb = oct * 8;
    const float* W = (col < 512) ? Wl : Wr;
    const int c = (col < 512) ? col : col - 512;
    ushort h[8], l[8];
    #pragma unroll
    for (int j = 0; j < 8; ++j) {
        int k = kb + j;
        float v = (k < FIN) ? W[(size_t)k * 512 + c] : 0.f;
        ushort hh = f2bf(v);
        h[j] = hh;
        l[j] = f2bf(v - bf2f(hh));
    }
    uint4 H, L;
    H.x = h[0] | (h[1] << 16); H.y = h[2] | (h[3] << 16);
    H.z = h[4] | (h[5] << 16); H.w = h[6] | (h[7] << 16);
    L.x = l[0] | (l[1] << 16); L.y = l[2] | (l[3] << 16);
    L.z = l[4] | (l[5] << 16); L.w = l[6] | (l[7] << 16);
    size_t slot = (size_t)oct * 1024 + col;
    ((uint4*)wh)[slot] = H;
    ((uint4*)wl)[slot] = L;
}

// ---- MFMA GEMM, bf16x3 split: [25088 x 1024] = x @ [Wl|Wr] ---------------
// 128x128 tile, 4 waves (2x2 of 64x64), 16x16x32 MFMA, f32-accurate.
__global__ __launch_bounds__(256, 2) void k_gemm3(
    const ushort* __restrict__ ah, const ushort* __restrict__ al,
    const ushort* __restrict__ wh, const ushort* __restrict__ wl,
    float* __restrict__ xl, float* __restrict__ xr)
{
    __shared__ __align__(16) ushort Ah[4096], Al[4096], Bh[4096], Bl[4096]; // 8KB ea
    const int tid = threadIdx.x;
    const int wid = tid >> 6, lane = tid & 63;
    const int row0 = blockIdx.y * 128;
    const int cb = blockIdx.x * 128;              // combined col base (bx fastest)
    const bool isR = cb >= 512;
    float* __restrict__ outp = isR ? xr : xl;
    const int oc0 = isR ? cb - 512 : cb;
    const int wr = wid >> 1, wc = wid & 1;
    const int s0 = tid, s1 = tid + 256;           // 2 of 512 slots per buffer

    uint4 rah0, rah1, ral0, ral1, rbh0, rbh1, rbl0, rbl1;
    auto load = [&](int t) {
        // slot s: kg = s>>7, idx = s&127 ; A global uint4 idx (t*4+kg)*RPAD+row0+idx
        int kg0 = s0 >> 7, i0 = s0 & 127;
        int kg1 = s1 >> 7, i1 = s1 & 127;
        size_t a0 = (size_t)(t * 4 + kg0) * RPAD + row0 + i0;
        size_t a1 = (size_t)(t * 4 + kg1) * RPAD + row0 + i1;
        size_t b0 = (size_t)(t * 4 + kg0) * 1024 + cb + i0;
        size_t b1 = (size_t)(t * 4 + kg1) * 1024 + cb + i1;
        rah0 = ((const uint4*)ah)[a0]; rah1 = ((const uint4*)ah)[a1];
        ral0 = ((const uint4*)al)[a0]; ral1 = ((const uint4*)al)[a1];
        rbh0 = ((const uint4*)wh)[b0]; rbh1 = ((const uint4*)wh)[b1];
        rbl0 = ((const uint4*)wl)[b0]; rbl1 = ((const uint4*)wl)[b1];
    };

    f32x4 acc[4][4];
    #pragma unroll
    for (int i = 0; i < 4; ++i)
        #pragma unroll
        for (int j = 0; j < 4; ++j) acc[i][j] = (f32x4)0.f;

    load(0);
    for (int t = 0; t < NT; ++t) {
        __syncthreads();                           // LDS free from prev step
        ((uint4*)Ah)[s0] = rah0; ((uint4*)Ah)[s1] = rah1;
        ((uint4*)Al)[s0] = ral0; ((uint4*)Al)[s1] = ral1;
        ((uint4*)Bh)[s0] = rbh0; ((uint4*)Bh)[s1] = rbh1;
        ((uint4*)Bl)[s0] = rbl0; ((uint4*)Bl)[s1] = rbl1;
        __syncthreads();
        if (t + 1 < NT) load(t + 1);               // hide next loads under MFMA
        const int kg = lane >> 4, r = lane & 15;
        bf16x8 fah[4], fal[4], fbh[4], fbl[4];
        #pragma unroll
        for (int i = 0; i < 4; ++i) {
            int sa = kg * 128 + wr * 64 + i * 16 + r;
            fah[i] = *(const bf16x8*)&Ah[sa * 8];
            fal[i] = *(const bf16x8*)&Al[sa * 8];
            int sb = kg * 128 + wc * 64 + i * 16 + r;
            fbh[i] = *(const bf16x8*)&Bh[sb * 8];
            fbl[i] = *(const bf16x8*)&Bl[sb * 8];
        }
        #pragma unroll
        for (int i = 0; i < 4; ++i)
            #pragma unroll
            for (int j = 0; j < 4; ++j)
                acc[i][j] = __builtin_amdgcn_mfma_f32_16x16x32_bf16(fah[i], fbh[j], acc[i][j], 0, 0, 0);
        #pragma unroll
        for (int i = 0; i < 4; ++i)
            #pragma unroll
            for (int j = 0; j < 4; ++j)
                acc[i][j] = __builtin_amdgcn_mfma_f32_16x16x32_bf16(fah[i], fbl[j], acc[i][j], 0, 0, 0);
        #pragma unroll
        for (int i = 0; i < 4; ++i)
            #pragma unroll
            for (int j = 0; j < 4; ++j)
                acc[i][j] = __builtin_amdgcn_mfma_f32_16x16x32_bf16(fal[i], fbh[j], acc[i][j], 0, 0, 0);
    }
    // epilogue: D col = lane&15, row = (lane>>4)*4 + rr   (m89 layout)
    const int cl = lane & 15, rq = lane >> 4;
    #pragma unroll
    for (int i = 0; i < 4; ++i) {
        #pragma unroll
        for (int rr = 0; rr < 4; ++rr) {
            int row = row0 + wr * 64 + i * 16 + rq * 4 + rr;
            if (row < NN) {
                #pragma unroll
                for (int j = 0; j < 4; ++j)
                    outp[(size_t)row * HCC + oc0 + wc * 64 + j * 16 + cl] = acc[i][j][rr];
            }
        }
    }
}

// ---------------- in-degree histogram over dst ----------------------------
__global__ __launch_bounds__(256) void k_count(const int* __restrict__ dst,
                                               int* __restrict__ cnt) {
    int e = blockIdx.x * 256 + threadIdx.x;
    if (e < EE) atomicAdd(&cnt[dst[e]], 1);
}

// ---------------- exclusive scan (single block, wave-shuffle) + dinv ------
__global__ __launch_bounds__(256) void k_scan(const int* __restrict__ cnt,
    int* __restrict__ offs, int* __restrict__ cursor, float* __restrict__ dinv)
{
    __shared__ int wsum[4];
    __shared__ int carry_s;
    const int tid = threadIdx.x;
    const int lane = tid & 63, wid = tid >> 6;
    if (tid == 0) carry_s = 0;
    __syncthreads();
    for (int base = 0; base < NN; base += 1024) {
        int i0 = base + tid * 4;
        int v[4];
        #pragma unroll
        for (int j = 0; j < 4; ++j) {
            int i = i0 + j;
            v[j] = (i < NN) ? cnt[i] : 0;
            if (i < NN) dinv[i] = rsqrtf((float)(v[j] + 1));
        }
        int tsum = v[0] + v[1] + v[2] + v[3];
        int s = tsum;
        #pragma unroll
        for (int off = 1; off < 64; off <<= 1) {
            int t = __shfl_up(s, off);
            if (lane >= off) s += t;
        }
        if (lane == 63) wsum[wid] = s;
        __syncthreads();
        int wcarry = carry_s;
        for (int w = 0; w < wid; ++w) wcarry += wsum[w];
        int ex = wcarry + s - tsum;
        #pragma unroll
        for (int j = 0; j < 4; ++j) {
            int i = i0 + j;
            if (i < NN) { offs[i] = ex; cursor[i] = ex; }
            ex += v[j];
        }
        __syncthreads();
        if (tid == 255) carry_s = wcarry + s;
        __syncthreads();
    }
    if (tid == 0) offs[NN] = carry_s;
}

// ---------------- scatter edges into CSR (by dst) -------------------------
__global__ __launch_bounds__(256) void k_scatter(const int* __restrict__ src,
    const int* __restrict__ dst, int* __restrict__ cursor, int* __restrict__ csr)
{
    int e = blockIdx.x * 256 + threadIdx.x;
    if (e < EE) {
        int d = dst[e];
        int pos = atomicAdd(&cursor[d], 1);
        csr[pos] = src[e];
    }
}

// ---------------- GATv2 per-node (one wave per dst) + BN/PReLU/Wg ---------
__global__ __launch_bounds__(256) void k_gat(
    const float* __restrict__ xl, const float* __restrict__ xr,
    const float* __restrict__ att, const float* __restrict__ b1,
    const float* __restrict__ gam, const float* __restrict__ bet,
    const float* __restrict__ mean, const float* __restrict__ var,
    const float* __restrict__ pw, const float* __restrict__ Wg,
    const int* __restrict__ offs, const int* __restrict__ csr,
    float* __restrict__ h2)
{
    const int lane = threadIdx.x & 63;
    const int node = blockIdx.x * 4 + (threadIdx.x >> 6);
    const int sb = lane * 8;
    float4 xr0 = *(const float4*)&xr[(size_t)node * HCC + sb];
    float4 xr1 = *(const float4*)&xr[(size_t)node * HCC + sb + 4];
    float4 a0 = *(const float4*)&att[sb];
    float4 a1 = *(const float4*)&att[sb + 4];
    float m = -3.0e38f, s = 0.f;
    float acc[8] = {0.f, 0.f, 0.f, 0.f, 0.f, 0.f, 0.f, 0.f};
    const int beg = offs[node], end = offs[node + 1];
    auto lrelu = [](float t) { return t >= 0.f ? t : 0.2f * t; };
    auto process = [&](int srcn) {
        const float* p = &xl[(size_t)srcn * HCC + sb];
        float4 v0 = *(const float4*)p;
        float4 v1 = *(const float4*)(p + 4);
        float ep = lrelu(v0.x + xr0.x) * a0.x + lrelu(v0.y + xr0.y) * a0.y
                 + lrelu(v0.z + xr0.z) * a0.z + lrelu(v0.w + xr0.w) * a0.w
                 + lrelu(v1.x + xr1.x) * a1.x + lrelu(v1.y + xr1.y) * a1.y
                 + lrelu(v1.z + xr1.z) * a1.z + lrelu(v1.w + xr1.w) * a1.w;
        ep += __shfl_xor(ep, 1);
        ep += __shfl_xor(ep, 2);
        ep += __shfl_xor(ep, 4);
        float mn = fmaxf(m, ep);
        float sc = __expf(m - mn);
        float w  = __expf(ep - mn);
        s = s * sc + w;
        float vv[8] = {v0.x, v0.y, v0.z, v0.w, v1.x, v1.y, v1.z, v1.w};
        #pragma unroll
        for (int k = 0; k < 8; ++k) acc[k] = acc[k] * sc + w * vv[k];
        m = mn;
    };
    process(node);
    for (int j = beg; j < end; ++j) process(csr[j]);
    float inv = 1.f / s;
    float p_w = pw[0];
    float dot = 0.f;
    #pragma unroll
    for (int k = 0; k < 8; ++k) {
        int idx = sb + k;
        float v = acc[k] * inv + b1[idx];
        v = (v - mean[idx]) * rsqrtf(var[idx] + 1e-5f) * gam[idx] + bet[idx];
        v = v >= 0.f ? v : p_w * v;
        dot += v * Wg[idx];
    }
    dot += __shfl_xor(dot, 1);
    dot += __shfl_xor(dot, 2);
    dot += __shfl_xor(dot, 4);
    dot += __shfl_xor(dot, 8);
    dot += __shfl_xor(dot, 16);
    dot += __shfl_xor(dot, 32);
    if (lane == 0) h2[node] = dot;
}

// ---------------- GCN: out[n] = dinv[n]*sum(dinv[src]*h2[src]) + bg -------
__global__ __launch_bounds__(256) void k_gcn(
    const float* __restrict__ h2, const float* __restrict__ dinv,
    const int* __restrict__ offs, const int* __restrict__ csr,
    const float* __restrict__ bg, float* __restrict__ out)
{
    int n = blockIdx.x * 256 + threadIdx.x;
    if (n >= NN) return;
    float dn = dinv[n];
    float s = dn * h2[n];
    int e0 = offs[n], e1 = offs[n + 1];
    for (int j = e0; j < e1; ++j) {
        int src = csr[j];
        s += dinv[src] * h2[src];
    }
    out[n] = dn * s + bg[0];
}

extern "C" void kernel_launch(void* const* d_in, const int* in_sizes, int n_in,
                              void* d_out, int out_size, void* d_ws, size_t ws_size,
                              hipStream_t stream)
{
    const float* x    = (const float*)d_in[0];
    const int*   ei   = (const int*)d_in[1];
    const float* Wl   = (const float*)d_in[2];
    const float* Wr   = (const float*)d_in[3];
    const float* att  = (const float*)d_in[4];
    const float* b1   = (const float*)d_in[5];
    const float* gam  = (const float*)d_in[6];
    const float* bet  = (const float*)d_in[7];
    const float* mean = (const float*)d_in[8];
    const float* var  = (const float*)d_in[9];
    const float* pw   = (const float*)d_in[10];
    const float* Wg   = (const float*)d_in[11];
    const float* bg   = (const float*)d_in[12];
    float* out = (float*)d_out;

    char* base = (char*)d_ws;
    size_t o = 0;
    float* xl   = (float*)(base + o); o += (size_t)NN * HCC * 4;   // 51.2 MB
    float* xr   = (float*)(base + o); o += (size_t)NN * HCC * 4;   // 51.2 MB
    float* h2   = (float*)(base + o); o += NN * 4;
    float* dinv = (float*)(base + o); o += NN * 4;
    int*   cnt  = (int*)(base + o);   o += NN * 4;
    int*   offs = (int*)(base + o);   o += (NN + 1) * 4;
    int*   cursor = (int*)(base + o); o += NN * 4;
    int*   csr  = (int*)(base + o);   o += (size_t)EE * 4;
    o = (o + 15) & ~(size_t)15;
    ushort* ah = (ushort*)(base + o); o += (size_t)RPAD * KPAD * 2; // 8.03 MB
    ushort* al = (ushort*)(base + o); o += (size_t)RPAD * KPAD * 2; // 8.03 MB
    ushort* wh = (ushort*)(base + o); o += (size_t)KPAD * 1024 * 2; // 327 KB
    ushort* wl = (ushort*)(base + o); o += (size_t)KPAD * 1024 * 2; // 327 KB

    const int* srcp = ei;
    const int* dstp = ei + EE;

    k_zero<<<(NN + 255) / 256, 256, 0, stream>>>(cnt);
    k_cvt_x<<<dim3(RPAD / 256, 20), 256, 0, stream>>>(x, ah, al);
    k_cvt_w<<<dim3(4, 20), 256, 0, stream>>>(Wl, Wr, wh, wl);
    k_gemm3<<<dim3(8, RPAD / 128), 256, 0, stream>>>(ah, al, wh, wl, xl, xr);
    k_count<<<(EE + 255) / 256, 256, 0, stream>>>(dstp, cnt);
    k_scan<<<1, 256, 0, stream>>>(cnt, offs, cursor, dinv);
    k_scatter<<<(EE + 255) / 256, 256, 0, stream>>>(srcp, dstp, cursor, csr);
    k_gat<<<NN / 4, 256, 0, stream>>>(xl, xr, att, b1, gam, bet, mean, var, pw, Wg,
                                      offs, csr, h2);
    k_gcn<<<(NN + 255) / 256, 256, 0, stream>>>(h2, dinv, offs, csr, bg, out);
}

// Round 5
// 321.014 us; speedup vs baseline: 1.7716x; 1.1251x over previous
//
#include <hip/hip_runtime.h>

#define NN 25000
#define EE 400000
#define FIN 133
#define HCC 512
#define RPAD 25088          // rows padded to 196*128
#define KPAD 160            // K padded to 5*32
#define NT 5                // K-steps of 32

typedef __attribute__((ext_vector_type(8))) __bf16 bf16x8;
typedef __attribute__((ext_vector_type(4))) float f32x4;
typedef __attribute__((ext_vector_type(8))) _Float16 f16x8;

static __device__ __forceinline__ ushort f2bf(float f) {
    uint32_t u = __float_as_uint(f);
    uint32_t r = (u + 0x7fffu + ((u >> 16) & 1u)) >> 16;   // RNE
    return (ushort)r;
}
static __device__ __forceinline__ float bf2f(ushort b) {
    return __uint_as_float(((uint32_t)b) << 16);
}

// ---------------- zero the degree counters (ws is poisoned each call) ------
__global__ __launch_bounds__(256) void k_zero(int* __restrict__ cnt) {
    int i = blockIdx.x * 256 + threadIdx.x;
    if (i < NN) cnt[i] = 0;
}

// ---- convert x -> blocked bf16 hi/lo: slot[(t*4+kg)*RPAD + row] = 8 k's ---
__global__ __launch_bounds__(256) void k_cvt_x(const float* __restrict__ x,
    ushort* __restrict__ ah, ushort* __restrict__ al)
{
    const int row = blockIdx.x * 256 + threadIdx.x;   // < RPAD (grid 98)
    const int oct = blockIdx.y;                       // 0..19, k base = oct*8
    const int kb = oct * 8;
    ushort h[8], l[8];
    #pragma unroll
    for (int j = 0; j < 8; ++j) {
        int k = kb + j;
        float v = (row < NN && k < FIN) ? x[(size_t)row * FIN + k] : 0.f;
        ushort hh = f2bf(v);
        h[j] = hh;
        l[j] = f2bf(v - bf2f(hh));
    }
    uint4 H, L;
    H.x = h[0] | (h[1] << 16); H.y = h[2] | (h[3] << 16);
    H.z = h[4] | (h[5] << 16); H.w = h[6] | (h[7] << 16);
    L.x = l[0] | (l[1] << 16); L.y = l[2] | (l[3] << 16);
    L.z = l[4] | (l[5] << 16); L.w = l[6] | (l[7] << 16);
    size_t slot = (size_t)oct * RPAD + row;
    ((uint4*)ah)[slot] = H;
    ((uint4*)al)[slot] = L;
}

// ---- convert [Wl|Wr] -> blocked bf16 hi/lo: slot[oct*1024 + col] ----------
__global__ __launch_bounds__(256) void k_cvt_w(
    const float* __restrict__ Wl, const float* __restrict__ Wr,
    ushort* __restrict__ wh, ushort* __restrict__ wl)
{
    const int col = blockIdx.x * 256 + threadIdx.x;   // 0..1023
    const int oct = blockIdx.y;                       // 0..19
    const int kb = oct * 8;
    const float* W = (col < 512) ? Wl : Wr;
    const int c = (col < 512) ? col : col - 512;
    ushort h[8], l[8];
    #pragma unroll
    for (int j = 0; j < 8; ++j) {
        int k = kb + j;
        float v = (k < FIN) ? W[(size_t)k * 512 + c] : 0.f;
        ushort hh = f2bf(v);
        h[j] = hh;
        l[j] = f2bf(v - bf2f(hh));
    }
    uint4 H, L;
    H.x = h[0] | (h[1] << 16); H.y = h[2] | (h[3] << 16);
    H.z = h[4] | (h[5] << 16); H.w = h[6] | (h[7] << 16);
    L.x = l[0] | (l[1] << 16); L.y = l[2] | (l[3] << 16);
    L.z = l[4] | (l[5] << 16); L.w = l[6] | (l[7] << 16);
    size_t slot = (size_t)oct * 1024 + col;
    ((uint4*)wh)[slot] = H;
    ((uint4*)wl)[slot] = L;
}

// ---- MFMA GEMM, bf16x3 split: [25088 x 1024] = x @ [Wl|Wr] ---------------
// 128x128 tile, 4 waves (2x2 of 64x64), 16x16x32 MFMA, f32-accurate.
// xl written as fp16 (gathered 17x downstream), xr as f32 (read once).
__global__ __launch_bounds__(256, 2) void k_gemm3(
    const ushort* __restrict__ ah, const ushort* __restrict__ al,
    const ushort* __restrict__ wh, const ushort* __restrict__ wl,
    ushort* __restrict__ xl, float* __restrict__ xr)
{
    __shared__ __align__(16) ushort Ah[4096], Al[4096], Bh[4096], Bl[4096]; // 8KB ea
    const int tid = threadIdx.x;
    const int wid = tid >> 6, lane = tid & 63;
    const int row0 = blockIdx.y * 128;
    const int cb = blockIdx.x * 128;              // combined col base (bx fastest)
    const bool isR = cb >= 512;
    const int oc0 = isR ? cb - 512 : cb;
    const int wr = wid >> 1, wc = wid & 1;
    const int s0 = tid, s1 = tid + 256;           // 2 of 512 slots per buffer

    uint4 rah0, rah1, ral0, ral1, rbh0, rbh1, rbl0, rbl1;
    auto load = [&](int t) {
        int kg0 = s0 >> 7, i0 = s0 & 127;
        int kg1 = s1 >> 7, i1 = s1 & 127;
        size_t a0 = (size_t)(t * 4 + kg0) * RPAD + row0 + i0;
        size_t a1 = (size_t)(t * 4 + kg1) * RPAD + row0 + i1;
        size_t b0 = (size_t)(t * 4 + kg0) * 1024 + cb + i0;
        size_t b1 = (size_t)(t * 4 + kg1) * 1024 + cb + i1;
        rah0 = ((const uint4*)ah)[a0]; rah1 = ((const uint4*)ah)[a1];
        ral0 = ((const uint4*)al)[a0]; ral1 = ((const uint4*)al)[a1];
        rbh0 = ((const uint4*)wh)[b0]; rbh1 = ((const uint4*)wh)[b1];
        rbl0 = ((const uint4*)wl)[b0]; rbl1 = ((const uint4*)wl)[b1];
    };

    f32x4 acc[4][4];
    #pragma unroll
    for (int i = 0; i < 4; ++i)
        #pragma unroll
        for (int j = 0; j < 4; ++j) acc[i][j] = (f32x4)0.f;

    load(0);
    for (int t = 0; t < NT; ++t) {
        __syncthreads();
        ((uint4*)Ah)[s0] = rah0; ((uint4*)Ah)[s1] = rah1;
        ((uint4*)Al)[s0] = ral0; ((uint4*)Al)[s1] = ral1;
        ((uint4*)Bh)[s0] = rbh0; ((uint4*)Bh)[s1] = rbh1;
        ((uint4*)Bl)[s0] = rbl0; ((uint4*)Bl)[s1] = rbl1;
        __syncthreads();
        if (t + 1 < NT) load(t + 1);
        const int kg = lane >> 4, r = lane & 15;
        bf16x8 fah[4], fal[4], fbh[4], fbl[4];
        #pragma unroll
        for (int i = 0; i < 4; ++i) {
            int sa = kg * 128 + wr * 64 + i * 16 + r;
            fah[i] = *(const bf16x8*)&Ah[sa * 8];
            fal[i] = *(const bf16x8*)&Al[sa * 8];
            int sb = kg * 128 + wc * 64 + i * 16 + r;
            fbh[i] = *(const bf16x8*)&Bh[sb * 8];
            fbl[i] = *(const bf16x8*)&Bl[sb * 8];
        }
        #pragma unroll
        for (int i = 0; i < 4; ++i)
            #pragma unroll
            for (int j = 0; j < 4; ++j)
                acc[i][j] = __builtin_amdgcn_mfma_f32_16x16x32_bf16(fah[i], fbh[j], acc[i][j], 0, 0, 0);
        #pragma unroll
        for (int i = 0; i < 4; ++i)
            #pragma unroll
            for (int j = 0; j < 4; ++j)
                acc[i][j] = __builtin_amdgcn_mfma_f32_16x16x32_bf16(fah[i], fbl[j], acc[i][j], 0, 0, 0);
        #pragma unroll
        for (int i = 0; i < 4; ++i)
            #pragma unroll
            for (int j = 0; j < 4; ++j)
                acc[i][j] = __builtin_amdgcn_mfma_f32_16x16x32_bf16(fal[i], fbh[j], acc[i][j], 0, 0, 0);
    }
    // epilogue: D col = lane&15, row = (lane>>4)*4 + rr   (m89 layout)
    const int cl = lane & 15, rq = lane >> 4;
    #pragma unroll
    for (int i = 0; i < 4; ++i) {
        #pragma unroll
        for (int rr = 0; rr < 4; ++rr) {
            int row = row0 + wr * 64 + i * 16 + rq * 4 + rr;
            if (row < NN) {
                if (isR) {
                    #pragma unroll
                    for (int j = 0; j < 4; ++j)
                        xr[(size_t)row * HCC + oc0 + wc * 64 + j * 16 + cl] = acc[i][j][rr];
                } else {
                    #pragma unroll
                    for (int j = 0; j < 4; ++j) {
                        _Float16 hv = (_Float16)acc[i][j][rr];
                        xl[(size_t)row * HCC + oc0 + wc * 64 + j * 16 + cl] =
                            *(const ushort*)&hv;
                    }
                }
            }
        }
    }
}

// ---------------- in-degree histogram over dst ----------------------------
__global__ __launch_bounds__(256) void k_count(const int* __restrict__ dst,
                                               int* __restrict__ cnt) {
    int e = blockIdx.x * 256 + threadIdx.x;
    if (e < EE) atomicAdd(&cnt[dst[e]], 1);
}

// ---------------- exclusive scan (single block, wave-shuffle) + dinv ------
__global__ __launch_bounds__(256) void k_scan(const int* __restrict__ cnt,
    int* __restrict__ offs, int* __restrict__ cursor, float* __restrict__ dinv)
{
    __shared__ int wsum[4];
    __shared__ int carry_s;
    const int tid = threadIdx.x;
    const int lane = tid & 63, wid = tid >> 6;
    if (tid == 0) carry_s = 0;
    __syncthreads();
    for (int base = 0; base < NN; base += 1024) {
        int i0 = base + tid * 4;
        int v[4];
        #pragma unroll
        for (int j = 0; j < 4; ++j) {
            int i = i0 + j;
            v[j] = (i < NN) ? cnt[i] : 0;
            if (i < NN) dinv[i] = rsqrtf((float)(v[j] + 1));
        }
        int tsum = v[0] + v[1] + v[2] + v[3];
        int s = tsum;
        #pragma unroll
        for (int off = 1; off < 64; off <<= 1) {
            int t = __shfl_up(s, off);
            if (lane >= off) s += t;
        }
        if (lane == 63) wsum[wid] = s;
        __syncthreads();
        int wcarry = carry_s;
        for (int w = 0; w < wid; ++w) wcarry += wsum[w];
        int ex = wcarry + s - tsum;
        #pragma unroll
        for (int j = 0; j < 4; ++j) {
            int i = i0 + j;
            if (i < NN) { offs[i] = ex; cursor[i] = ex; }
            ex += v[j];
        }
        __syncthreads();
        if (tid == 255) carry_s = wcarry + s;
        __syncthreads();
    }
    if (tid == 0) offs[NN] = carry_s;
}

// ---------------- scatter edges into CSR (by dst) -------------------------
__global__ __launch_bounds__(256) void k_scatter(const int* __restrict__ src,
    const int* __restrict__ dst, int* __restrict__ cursor, int* __restrict__ csr)
{
    int e = blockIdx.x * 256 + threadIdx.x;
    if (e < EE) {
        int d = dst[e];
        int pos = atomicAdd(&cursor[d], 1);
        csr[pos] = src[e];
    }
}

// ---------------- GATv2 per-node (one wave per dst) + BN/PReLU/Wg ---------
// xl gathered as fp16 (16B/lane), xr/att/params f32.
__global__ __launch_bounds__(256) void k_gat(
    const ushort* __restrict__ xl, const float* __restrict__ xr,
    const float* __restrict__ att, const float* __restrict__ b1,
    const float* __restrict__ gam, const float* __restrict__ bet,
    const float* __restrict__ mean, const float* __restrict__ var,
    const float* __restrict__ pw, const float* __restrict__ Wg,
    const int* __restrict__ offs, const int* __restrict__ csr,
    float* __restrict__ h2)
{
    const int lane = threadIdx.x & 63;
    const int node = blockIdx.x * 4 + (threadIdx.x >> 6);  // grid = NN/4 exactly
    const int sb = lane * 8;
    float xrv[8], av[8];
    #pragma unroll
    for (int k = 0; k < 8; ++k) {
        xrv[k] = xr[(size_t)node * HCC + sb + k];
        av[k]  = att[sb + k];
    }
    float m = -3.0e38f, s = 0.f;
    float acc[8] = {0.f, 0.f, 0.f, 0.f, 0.f, 0.f, 0.f, 0.f};
    const int beg = offs[node], end = offs[node + 1];
    auto lrelu = [](float t) { return t >= 0.f ? t : 0.2f * t; };
    auto process = [&](f16x8 hv) {
        float v[8];
        #pragma unroll
        for (int k = 0; k < 8; ++k) v[k] = (float)hv[k];
        float ep = 0.f;
        #pragma unroll
        for (int k = 0; k < 8; ++k) ep += lrelu(v[k] + xrv[k]) * av[k];
        ep += __shfl_xor(ep, 1);
        ep += __shfl_xor(ep, 2);
        ep += __shfl_xor(ep, 4);        // head logit, replicated in 8-lane group
        float mn = fmaxf(m, ep);
        float sc = __expf(m - mn);
        float w  = __expf(ep - mn);
        s = s * sc + w;
        #pragma unroll
        for (int k = 0; k < 8; ++k) acc[k] = acc[k] * sc + w * v[k];
        m = mn;
    };
    auto row = [&](int srcn) -> f16x8 {
        return *(const f16x8*)&xl[(size_t)srcn * HCC + sb];
    };
    process(row(node));                     // self loop
    int j = beg;
    for (; j + 2 <= end; j += 2) {          // 2 independent gathers in flight
        int sA = csr[j], sB = csr[j + 1];
        f16x8 hA = row(sA);
        f16x8 hB = row(sB);
        process(hA);
        process(hB);
    }
    if (j < end) process(row(csr[j]));
    float inv = 1.f / s;
    float p_w = pw[0];
    float dot = 0.f;
    #pragma unroll
    for (int k = 0; k < 8; ++k) {
        int idx = sb + k;
        float v = acc[k] * inv + b1[idx];
        v = (v - mean[idx]) * rsqrtf(var[idx] + 1e-5f) * gam[idx] + bet[idx];
        v = v >= 0.f ? v : p_w * v;
        dot += v * Wg[idx];
    }
    dot += __shfl_xor(dot, 1);
    dot += __shfl_xor(dot, 2);
    dot += __shfl_xor(dot, 4);
    dot += __shfl_xor(dot, 8);
    dot += __shfl_xor(dot, 16);
    dot += __shfl_xor(dot, 32);
    if (lane == 0) h2[node] = dot;
}

// ---------------- GCN: out[n] = dinv[n]*sum(dinv[src]*h2[src]) + bg -------
__global__ __launch_bounds__(256) void k_gcn(
    const float* __restrict__ h2, const float* __restrict__ dinv,
    const int* __restrict__ offs, const int* __restrict__ csr,
    const float* __restrict__ bg, float* __restrict__ out)
{
    int n = blockIdx.x * 256 + threadIdx.x;
    if (n >= NN) return;
    float dn = dinv[n];
    float s = dn * h2[n];
    int e0 = offs[n], e1 = offs[n + 1];
    for (int j = e0; j < e1; ++j) {
        int src = csr[j];
        s += dinv[src] * h2[src];
    }
    out[n] = dn * s + bg[0];
}

extern "C" void kernel_launch(void* const* d_in, const int* in_sizes, int n_in,
                              void* d_out, int out_size, void* d_ws, size_t ws_size,
                              hipStream_t stream)
{
    const float* x    = (const float*)d_in[0];
    const int*   ei   = (const int*)d_in[1];
    const float* Wl   = (const float*)d_in[2];
    const float* Wr   = (const float*)d_in[3];
    const float* att  = (const float*)d_in[4];
    const float* b1   = (const float*)d_in[5];
    const float* gam  = (const float*)d_in[6];
    const float* bet  = (const float*)d_in[7];
    const float* mean = (const float*)d_in[8];
    const float* var  = (const float*)d_in[9];
    const float* pw   = (const float*)d_in[10];
    const float* Wg   = (const float*)d_in[11];
    const float* bg   = (const float*)d_in[12];
    float* out = (float*)d_out;

    char* base = (char*)d_ws;
    size_t o = 0;
    ushort* xl  = (ushort*)(base + o); o += (size_t)NN * HCC * 2;  // 25.6 MB fp16
    o = (o + 15) & ~(size_t)15;
    float* xr   = (float*)(base + o); o += (size_t)NN * HCC * 4;   // 51.2 MB
    float* h2   = (float*)(base + o); o += NN * 4;
    float* dinv = (float*)(base + o); o += NN * 4;
    int*   cnt  = (int*)(base + o);   o += NN * 4;
    int*   offs = (int*)(base + o);   o += (NN + 1) * 4;
    int*   cursor = (int*)(base + o); o += NN * 4;
    int*   csr  = (int*)(base + o);   o += (size_t)EE * 4;
    o = (o + 15) & ~(size_t)15;
    ushort* ah = (ushort*)(base + o); o += (size_t)RPAD * KPAD * 2; // 8.03 MB
    ushort* al = (ushort*)(base + o); o += (size_t)RPAD * KPAD * 2; // 8.03 MB
    ushort* wh = (ushort*)(base + o); o += (size_t)KPAD * 1024 * 2; // 327 KB
    ushort* wl = (ushort*)(base + o); o += (size_t)KPAD * 1024 * 2; // 327 KB

    const int* srcp = ei;
    const int* dstp = ei + EE;

    k_zero<<<(NN + 255) / 256, 256, 0, stream>>>(cnt);
    k_cvt_x<<<dim3(RPAD / 256, 20), 256, 0, stream>>>(x, ah, al);
    k_cvt_w<<<dim3(4, 20), 256, 0, stream>>>(Wl, Wr, wh, wl);
    k_gemm3<<<dim3(8, RPAD / 128), 256, 0, stream>>>(ah, al, wh, wl, xl, xr);
    k_count<<<(EE + 255) / 256, 256, 0, stream>>>(dstp, cnt);
    k_scan<<<1, 256, 0, stream>>>(cnt, offs, cursor, dinv);
    k_scatter<<<(EE + 255) / 256, 256, 0, stream>>>(srcp, dstp, cursor, csr);
    k_gat<<<NN / 4, 256, 0, stream>>>(xl, xr, att, b1, gam, bet, mean, var, pw, Wg,
                                      offs, csr, h2);
    k_gcn<<<(NN + 255) / 256, 256, 0, stream>>>(h2, dinv, offs, csr, bg, out);
}